// Round 2
// 269.041 us; speedup vs baseline: 1.0426x; 1.0426x over previous
//
#include <hip/hip_runtime.h>
#include <hip/hip_bf16.h>

typedef __attribute__((ext_vector_type(8))) short short8;
typedef __attribute__((ext_vector_type(4))) short short4v;
typedef __attribute__((ext_vector_type(4))) float floatx4;
typedef unsigned short u16;

#define B_SZ 4
#define NH   16
#define SEQ  2048
#define DM   1024
#define DK   64
#define M_ROWS (B_SZ * SEQ)   // 8192

__device__ __forceinline__ u16 f2bf(float f) {
  unsigned u = __float_as_uint(f);
  u += 0x7fff + ((u >> 16) & 1);   // RNE
  return (u16)(u >> 16);
}

// async global->LDS: dest = wave-uniform base + lane*16B (verified constraint)
__device__ __forceinline__ void async_copy16(const u16* g, const short* lds) {
  __builtin_amdgcn_global_load_lds(
      (const __attribute__((address_space(1))) void*)g,
      (__attribute__((address_space(3))) void*)lds,
      16, 0, 0);
}

#define BAR() do { __builtin_amdgcn_s_barrier(); asm volatile("" ::: "memory"); } while (0)
#define WAIT_LGKM0() asm volatile("s_waitcnt lgkmcnt(0)" ::: "memory")

// ---------------------------------------------------------------------------
// cvt4: fp32->bf16 for x (y=0) and Wq/Wk/Wv (y=1..3). grid=(1024,4).
// ---------------------------------------------------------------------------
__global__ __launch_bounds__(256)
void cvt4_kernel(const float* __restrict__ x,
                 const float* __restrict__ wq, const float* __restrict__ wk,
                 const float* __restrict__ wv,
                 u16* __restrict__ xb, u16* __restrict__ wb)
{
  const int y = blockIdx.y;
  const float* src; u16* dst; int n4;
  if (y == 0)      { src = x;  dst = xb;                 n4 = (M_ROWS * DM) / 4; }
  else if (y == 1) { src = wq; dst = wb;                 n4 = (DM * DM) / 4; }
  else if (y == 2) { src = wk; dst = wb + DM * DM;       n4 = (DM * DM) / 4; }
  else             { src = wv; dst = wb + 2 * DM * DM;   n4 = (DM * DM) / 4; }
  for (int i = blockIdx.x * 256 + threadIdx.x; i < n4; i += gridDim.x * 256) {
    floatx4 v = ((const floatx4*)src)[i];
    short4v s;
#pragma unroll
    for (int e = 0; e < 4; ++e) s[e] = (short)f2bf(v[e]);
    ((short4v*)dst)[i] = s;
  }
}

__global__ __launch_bounds__(256)
void cvt1_kernel(const float* __restrict__ in, u16* __restrict__ out, int n4)
{
  for (int i = blockIdx.x * 256 + threadIdx.x; i < n4; i += gridDim.x * 256) {
    floatx4 v = ((const floatx4*)in)[i];
    short4v s;
#pragma unroll
    for (int e = 0; e < 4; ++e) s[e] = (short)f2bf(v[e]);
    ((short4v*)out)[i] = s;
  }
}

// ---------------------------------------------------------------------------
// 256x256 / BK=64 / 8-wave / 8-phase GEMM core (T2+T3+T4+T5 template).
// C = A(Mx1024 bf16 rm) * B^T (B Nx1024 bf16 rm).  K = 1024 -> 16 K-tiles,
// double-buffered (buf0 = even tiles, buf1 = odd), 8 iterations x 2 tiles.
//
// LDS swizzle (T2): LDS[row][cu] holds global (row, cu ^ (row&7)); staged via
// pre-swizzled global source (linear global_load_lds dest), read back with the
// same XOR on the ds_read_b128 address (bijective per 8-row stripe).
//
// REGION LEDGER (race-fix from round 0 -- stage R only after the closing
// barrier of the last phase whose ds_reads touch R):
//   A rows read in phases 1 (lo 64) and 3 (hi 64)  -> A dead after ph3 close
//   B rows read in phases 1 (n-lo) and 2 (n-hi)    -> B dead after ph2 close
//   => stage B(next) in phase 3, stage A(next) in phase 4.  (Round 0 staged
//   A in phase 2, racing phase 3's A reads -> absmax 0.746.)
//
// vmcnt (T4): 8 loads/thread per K-tile, all issued in phases 3-4 of the
// PREVIOUS same-buffer tile.  At phase 4, vmcnt(8) leaves exactly the newest
// tile's 8 loads in flight => tile t+1 verified landed before its phase 1.
// Final two tiles (no staging) drain with vmcnt(0).
// ---------------------------------------------------------------------------
__device__ __forceinline__ void stage_tile_half(
    const u16* __restrict__ src,   // element (row0_of_half, k0)
    short* dst,                    // LDS base of this 128x64 half
    int wid, int lane)
{
#pragma unroll
  for (int j = 0; j < 2; ++j) {
    const int oct = wid + j * 8;                 // 0..15 (8 rows each)
    const int row = oct * 8 + (lane >> 3);
    const int cu  = (lane & 7) ^ (lane >> 3);    // pre-swizzled col-unit (16B)
    async_copy16(src + (size_t)row * DM + cu * 8, dst + oct * 512);
  }
}

__device__ __forceinline__ void gemm256_core(
    const u16* __restrict__ A, const u16* __restrict__ B,
    int m0, int n0, floatx4 acc[8][4])
{
  __shared__ short smem[65536];                  // 128 KiB: 2 x (A 16K + B 16K)

  const int tid  = threadIdx.x;
  const int wid  = tid >> 6;
  const int lane = tid & 63;
  const int wm   = wid >> 2, wn = wid & 3;       // wave grid 2(M) x 4(N)
  const int quad = lane >> 4, l16 = lane & 15;
  const int swz  = l16 & 7;                      // row&7 == l16&7 for all frags

  short* sA_[2] = { smem,         smem + 32768 };
  short* sB_[2] = { smem + 16384, smem + 49152 };

#pragma unroll
  for (int mi = 0; mi < 8; ++mi)
#pragma unroll
    for (int ni = 0; ni < 4; ++ni)
      acc[mi][ni] = floatx4{0.f, 0.f, 0.f, 0.f};

  const u16* Abase = A + (size_t)m0 * DM;
  const u16* Bbase = B + (size_t)n0 * DM;

  // ---- prologue: stage tiles 0 (buf0) and 1 (buf1), 8 loads each ----
#pragma unroll
  for (int t = 0; t < 2; ++t) {
    const int kof = t * 64;
    stage_tile_half(Abase + kof,                    sA_[t],        wid, lane);
    stage_tile_half(Abase + (size_t)128 * DM + kof, sA_[t] + 8192, wid, lane);
    stage_tile_half(Bbase + kof,                    sB_[t],        wid, lane);
    stage_tile_half(Bbase + (size_t)128 * DM + kof, sB_[t] + 8192, wid, lane);
  }
  asm volatile("s_waitcnt vmcnt(8)" ::: "memory");   // tile0 landed
  BAR();

  short8 af[4][2], bf0[2][2], bf1[2][2];

  for (int i = 0; i < 8; ++i) {                  // tiles 2i, 2i+1
    const bool nl = (i < 7);                     // stage tiles 2i+2 / 2i+3
#pragma unroll
    for (int half = 0; half < 2; ++half) {
      short* cA = sA_[half];
      short* cB = sB_[half];
      const int kof_n = (2 * i + 2 + half) * 64; // staging k-offset (if nl)

      // ---- phase 1: ds_read A-lo (8) + B-lo (4); MFMA m-lo x n-lo ----
#pragma unroll
      for (int mi = 0; mi < 4; ++mi)
#pragma unroll
        for (int kk = 0; kk < 2; ++kk)
          af[mi][kk] = *(const short8*)(cA + (wm * 128 + mi * 16 + l16) * 64
                                           + (((kk * 4 + quad) ^ swz) << 3));
#pragma unroll
      for (int ni = 0; ni < 2; ++ni)
#pragma unroll
        for (int kk = 0; kk < 2; ++kk)
          bf0[ni][kk] = *(const short8*)(cB + (wn * 64 + ni * 16 + l16) * 64
                                            + (((kk * 4 + quad) ^ swz) << 3));
      BAR();
      WAIT_LGKM0();
      __builtin_amdgcn_s_setprio(1);
#pragma unroll
      for (int mi = 0; mi < 4; ++mi)
#pragma unroll
        for (int ni = 0; ni < 2; ++ni)
#pragma unroll
          for (int kk = 0; kk < 2; ++kk)
            acc[mi][ni] = __builtin_amdgcn_mfma_f32_16x16x32_bf16(
                af[mi][kk], bf0[ni][kk], acc[mi][ni], 0, 0, 0);
      __builtin_amdgcn_s_setprio(0);
      BAR();

      // ---- phase 2: ds_read B-hi (4); MFMA m-lo x n-hi ----
#pragma unroll
      for (int ni = 0; ni < 2; ++ni)
#pragma unroll
        for (int kk = 0; kk < 2; ++kk)
          bf1[ni][kk] = *(const short8*)(cB + (wn * 64 + (2 + ni) * 16 + l16) * 64
                                            + (((kk * 4 + quad) ^ swz) << 3));
      BAR();
      WAIT_LGKM0();
      __builtin_amdgcn_s_setprio(1);
#pragma unroll
      for (int mi = 0; mi < 4; ++mi)
#pragma unroll
        for (int ni = 0; ni < 2; ++ni)
#pragma unroll
          for (int kk = 0; kk < 2; ++kk)
            acc[mi][2 + ni] = __builtin_amdgcn_mfma_f32_16x16x32_bf16(
                af[mi][kk], bf1[ni][kk], acc[mi][2 + ni], 0, 0, 0);
      __builtin_amdgcn_s_setprio(0);
      BAR();

      // ---- phase 3: ds_read A-hi (8, reuse af); stage B(next) both halves;
      //      MFMA m-hi x n-hi ----  (B reads all drained by ph2 close)
#pragma unroll
      for (int mi = 0; mi < 4; ++mi)
#pragma unroll
        for (int kk = 0; kk < 2; ++kk)
          af[mi][kk] = *(const short8*)(cA + (wm * 128 + (4 + mi) * 16 + l16) * 64
                                           + (((kk * 4 + quad) ^ swz) << 3));
      if (nl) {
        stage_tile_half(Bbase + kof_n,                    cB,        wid, lane);
        stage_tile_half(Bbase + (size_t)128 * DM + kof_n, cB + 8192, wid, lane);
      }
      BAR();
      WAIT_LGKM0();
      __builtin_amdgcn_s_setprio(1);
#pragma unroll
      for (int mi = 0; mi < 4; ++mi)
#pragma unroll
        for (int ni = 0; ni < 2; ++ni)
#pragma unroll
          for (int kk = 0; kk < 2; ++kk)
            acc[4 + mi][2 + ni] = __builtin_amdgcn_mfma_f32_16x16x32_bf16(
                af[mi][kk], bf1[ni][kk], acc[4 + mi][2 + ni], 0, 0, 0);
      __builtin_amdgcn_s_setprio(0);
      BAR();

      // ---- phase 4: stage A(next) both halves; counted vmcnt;
      //      MFMA m-hi x n-lo ----  (A reads all drained by ph3 close)
      if (nl) {
        stage_tile_half(Abase + kof_n,                    cA,        wid, lane);
        stage_tile_half(Abase + (size_t)128 * DM + kof_n, cA + 8192, wid, lane);
        asm volatile("s_waitcnt vmcnt(8)" ::: "memory");  // tile t+1 landed
      } else {
        asm volatile("s_waitcnt vmcnt(0)" ::: "memory");  // drain final tiles
      }
      BAR();
      __builtin_amdgcn_s_setprio(1);
#pragma unroll
      for (int mi = 0; mi < 4; ++mi)
#pragma unroll
        for (int ni = 0; ni < 2; ++ni)
#pragma unroll
          for (int kk = 0; kk < 2; ++kk)
            acc[4 + mi][ni] = __builtin_amdgcn_mfma_f32_16x16x32_bf16(
                af[mi][kk], bf0[ni][kk], acc[4 + mi][ni], 0, 0, 0);
      __builtin_amdgcn_s_setprio(0);
      BAR();
    }
  }
}

// ---------------------------------------------------------------------------
// Fused QKV projection, 256^2 tiles. grid = (384): [0,128) Q, [128,256) K,
// [256,384) V^T (operands swapped: C[e][s] = sum_d Wv[e][d] x[s][d], so the
// (b,h,d,s) store is contiguous in s -- no 4KB-stride scatter).
// ---------------------------------------------------------------------------
__global__ __launch_bounds__(512, 2)
void qkv256_kernel(const u16* __restrict__ xb, const u16* __restrict__ wb,
                   const float* __restrict__ bq, const float* __restrict__ bk,
                   const float* __restrict__ bv,
                   u16* __restrict__ Qo, u16* __restrict__ Ko, u16* __restrict__ Vto)
{
  const int bx = blockIdx.x;
  const int wg = (bx & 7) * 48 + (bx >> 3);      // bijective XCD swizzle (384%8==0)
  const int mat = wg >> 7;
  const int r   = wg & 127;

  int m0, n0;
  const u16 *A, *Bm;
  if (mat < 2) { m0 = (r >> 2) * 256; n0 = (r & 3) * 256; A = xb; Bm = wb + (size_t)mat * DM * DM; }
  else         { m0 = (r & 3) * 256;  n0 = (r >> 2) * 256; A = wb + (size_t)2 * DM * DM; Bm = xb; }

  floatx4 acc[8][4];
  gemm256_core(A, Bm, m0, n0, acc);

  const int tid = threadIdx.x;
  const int wid = tid >> 6, lane = tid & 63;
  const int wm = wid >> 2, wn = wid & 3;
  const int quad = lane >> 4, l16 = lane & 15;

  if (mat < 2) {
    u16* dst = (mat == 0) ? Qo : Ko;
    const float* bias = (mat == 0) ? bq : bk;
#pragma unroll
    for (int ni = 0; ni < 4; ++ni) {
      const int n = n0 + wn * 64 + ni * 16 + l16;
      const float bb = bias[n];
      const int h = n >> 6, d = n & 63;
#pragma unroll
      for (int mi = 0; mi < 8; ++mi)
#pragma unroll
        for (int rr = 0; rr < 4; ++rr) {
          const int m = m0 + wm * 128 + mi * 16 + quad * 4 + rr;
          const int b = m >> 11, s = m & 2047;
          dst[((size_t)(b * NH + h) * SEQ + s) * DK + d] = f2bf(acc[mi][ni][rr] + bb);
        }
    }
  } else {
#pragma unroll
    for (int mi = 0; mi < 8; ++mi)
#pragma unroll
      for (int rr = 0; rr < 4; ++rr) {
        const int m = m0 + wm * 128 + mi * 16 + quad * 4 + rr;   // e in [0,1024)
        const float bb = bv[m];
        const int h = m >> 6, d = m & 63;
#pragma unroll
        for (int ni = 0; ni < 4; ++ni) {
          const int n = n0 + wn * 64 + ni * 16 + l16;            // (b,s) in [0,8192)
          const int b = n >> 11, s = n & 2047;
          Vto[((size_t)(b * NH + h) * DK + d) * SEQ + s] = f2bf(acc[mi][ni][rr] + bb);
        }
      }
  }
}

// ---------------------------------------------------------------------------
// Flash attention, causal, exp2-domain, no-rescale online softmax.
// grid = (64 bh, 16 qt-reversed). Block = 128 q-rows, 4 waves x 32 rows.
// (unchanged -- next round's target)
// ---------------------------------------------------------------------------
#define AT_STR 72
__global__ __launch_bounds__(256, 2)
void attn_kernel(const u16* __restrict__ Q, const u16* __restrict__ Kx,
                 const u16* __restrict__ Vt, u16* __restrict__ O)
{
  __shared__ short Ks[64 * 64];
  __shared__ short Vs[64 * 64];
  __shared__ short Ps[4 * 32 * AT_STR];

  const int bh  = blockIdx.x;
  const int qtb = 15 - (int)blockIdx.y;
  const int q0  = qtb * 128;
  const int tid = threadIdx.x;
  const int w = tid >> 6, lane = tid & 63;
  const int quad = lane >> 4, l16 = lane & 15;
  const int r8 = lane >> 3, c8 = lane & 7;

  const u16* Qh = Q  + (size_t)bh * SEQ * DK;
  const u16* Kh = Kx + (size_t)bh * SEQ * DK;
  const u16* Vh = Vt + (size_t)bh * DK * SEQ;

  short8 qf[2][2];
#pragma unroll
  for (int qp = 0; qp < 2; ++qp) {
    const int qrow = q0 + w * 32 + qp * 16 + l16;
#pragma unroll
    for (int h = 0; h < 2; ++h)
      qf[qp][h] = *(const short8*)(Qh + (size_t)qrow * DK + h * 32 + quad * 8);
  }

  short8 vone;
#pragma unroll
  for (int j = 0; j < 8; ++j) vone[j] = (l16 == 0) ? (short)0x3F80 : (short)0;

  floatx4 o[2][4], ls[2];
#pragma unroll
  for (int qp = 0; qp < 2; ++qp) {
    ls[qp] = floatx4{0.f, 0.f, 0.f, 0.f};
#pragma unroll
    for (int dt = 0; dt < 4; ++dt) o[qp][dt] = floatx4{0.f, 0.f, 0.f, 0.f};
  }

  const float SC2 = 0.18033688011f;   // (1/8) * log2(e)
  const int ktmax = 2 * qtb + 2;

  for (int kt = 0; kt < ktmax; ++kt) {
    const int k0 = kt * 64;
    __syncthreads();
#pragma unroll
    for (int c = 0; c < 2; ++c) {
      const int row8 = w * 16 + c * 8;   // wave-uniform
      const int sw   = (c8 ^ r8) * 8;
      async_copy16(Kh + (size_t)(k0 + row8 + r8) * DK + sw, Ks + row8 * 64);
      async_copy16(Vh + (size_t)(row8 + r8) * SEQ + k0 + sw, Vs + row8 * 64);
    }
    __syncthreads();

    short8 kf[4][2], vf[4][2];
#pragma unroll
    for (int nt = 0; nt < 4; ++nt)
#pragma unroll
      for (int h = 0; h < 2; ++h) {
        kf[nt][h] = *(const short8*)(Ks + (nt * 16 + l16) * 64 + (((h * 4 + quad) ^ (l16 & 7)) * 8));
        vf[nt][h] = *(const short8*)(Vs + (nt * 16 + l16) * 64 + (((h * 4 + quad) ^ (l16 & 7)) * 8));
      }

#pragma unroll
    for (int qp = 0; qp < 2; ++qp) {
      const int frag0 = q0 + w * 32 + qp * 16;
      if (k0 <= frag0 + 15) {
        floatx4 sc[4];
#pragma unroll
        for (int nt = 0; nt < 4; ++nt) {
          floatx4 z = floatx4{0.f, 0.f, 0.f, 0.f};
          z = __builtin_amdgcn_mfma_f32_16x16x32_bf16(qf[qp][0], kf[nt][0], z, 0, 0, 0);
          z = __builtin_amdgcn_mfma_f32_16x16x32_bf16(qf[qp][1], kf[nt][1], z, 0, 0, 0);
          sc[nt] = z;
        }
        const bool diag = (k0 + 63 > frag0);
#pragma unroll
        for (int nt = 0; nt < 4; ++nt)
#pragma unroll
          for (int r = 0; r < 4; ++r) {
            float s = sc[nt][r] * SC2;
            if (diag) {
              const int col = k0 + nt * 16 + l16;
              const int row = frag0 + quad * 4 + r;
              if (col > row) s = -1e30f;
            }
            sc[nt][r] = __builtin_amdgcn_exp2f(s);
          }
        short* Pp = Ps + (w * 32 + qp * 16) * AT_STR;
#pragma unroll
        for (int nt = 0; nt < 4; ++nt)
#pragma unroll
          for (int r = 0; r < 4; ++r)
            Pp[(quad * 4 + r) * AT_STR + nt * 16 + l16] = (short)f2bf(sc[nt][r]);
        short8 pf[2];
#pragma unroll
        for (int h = 0; h < 2; ++h)
          pf[h] = *(const short8*)(Pp + l16 * AT_STR + h * 32 + quad * 8);
#pragma unroll
        for (int dt = 0; dt < 4; ++dt) {
          o[qp][dt] = __builtin_amdgcn_mfma_f32_16x16x32_bf16(pf[0], vf[dt][0], o[qp][dt], 0, 0, 0);
          o[qp][dt] = __builtin_amdgcn_mfma_f32_16x16x32_bf16(pf[1], vf[dt][1], o[qp][dt], 0, 0, 0);
        }
        ls[qp] = __builtin_amdgcn_mfma_f32_16x16x32_bf16(pf[0], vone, ls[qp], 0, 0, 0);
        ls[qp] = __builtin_amdgcn_mfma_f32_16x16x32_bf16(pf[1], vone, ls[qp], 0, 0, 0);
      }
    }
  }

  const int b = bh >> 4, h = bh & 15;
#pragma unroll
  for (int qp = 0; qp < 2; ++qp) {
    const int frag0 = q0 + w * 32 + qp * 16;
#pragma unroll
    for (int r = 0; r < 4; ++r) {
      const float lv  = __shfl(ls[qp][r], lane & 48);
      const float inv = 1.0f / fmaxf(lv, 1e-20f);
      const int row   = frag0 + quad * 4 + r;
      const size_t base = ((size_t)b * SEQ + row) * DM + h * DK;
#pragma unroll
      for (int dt = 0; dt < 4; ++dt)
        O[base + dt * 16 + l16] = f2bf(o[qp][dt][r] * inv);
    }
  }
}

// ---------------------------------------------------------------------------
// Output projection: out = O'(bf16) @ Wo_b^T + bo, fp32 out. grid = (128).
// ---------------------------------------------------------------------------
__global__ __launch_bounds__(512, 2)
void oproj256_kernel(const u16* __restrict__ A, const u16* __restrict__ Wob,
                     const float* __restrict__ bo, float* __restrict__ out)
{
  const int bx = blockIdx.x;
  const int wg = (bx & 7) * 16 + (bx >> 3);      // 128 % 8 == 0
  const int m0 = (wg >> 2) * 256, n0 = (wg & 3) * 256;

  floatx4 acc[8][4];
  gemm256_core(A, Wob, m0, n0, acc);

  const int tid = threadIdx.x;
  const int wid = tid >> 6, lane = tid & 63;
  const int wm = wid >> 2, wn = wid & 3;
  const int quad = lane >> 4, l16 = lane & 15;

#pragma unroll
  for (int ni = 0; ni < 4; ++ni) {
    const int n = n0 + wn * 64 + ni * 16 + l16;
    const float bb = bo[n];
#pragma unroll
    for (int mi = 0; mi < 8; ++mi)
#pragma unroll
      for (int rr = 0; rr < 4; ++rr) {
        const int m = m0 + wm * 128 + mi * 16 + quad * 4 + rr;
        out[(size_t)m * DM + n] = acc[mi][ni][rr] + bb;
      }
  }
}

extern "C" void kernel_launch(void* const* d_in, const int* in_sizes, int n_in,
                              void* d_out, int out_size, void* d_ws, size_t ws_size,
                              hipStream_t stream)
{
  const float* x  = (const float*)d_in[0];
  const float* Wq = (const float*)d_in[1];
  const float* bq = (const float*)d_in[2];
  const float* Wk = (const float*)d_in[3];
  const float* bk = (const float*)d_in[4];
  const float* Wv = (const float*)d_in[5];
  const float* bv = (const float*)d_in[6];
  const float* Wo = (const float*)d_in[7];
  const float* bo = (const float*)d_in[8];
  float* out = (float*)d_out;

  // ws (64 MiB): Q, K, Vt, O'  (qws doubles as Wo_b after attn)
  u16* qws  = (u16*)d_ws;                       // (b,h,s,d)  bf16, 16 MiB
  u16* kws  = qws  + (size_t)M_ROWS * DM;       // (b,h,s,d)  bf16, 16 MiB
  u16* vtws = kws  + (size_t)M_ROWS * DM;       // (b,h,d,s)  bf16, 16 MiB
  u16* ows  = vtws + (size_t)M_ROWS * DM;       // O' (b,s,h*d) bf16, 16 MiB

  // d_out doubles as scratch until oproj overwrites all of it:
  //   [0, 16 MiB)  : x bf16
  //   [16, 22 MiB) : Wq/Wk/Wv bf16 packed [3][DM][DM]
  u16* xb = (u16*)d_out;
  u16* wb = xb + (size_t)M_ROWS * DM;
  u16* wo_b = qws;                              // qws dead after attn

  cvt4_kernel  <<<dim3(1024, 4), 256, 0, stream>>>(x, Wq, Wk, Wv, xb, wb);
  qkv256_kernel<<<dim3(384), 512, 0, stream>>>(xb, wb, bq, bk, bv, qws, kws, vtws);
  attn_kernel  <<<dim3(64, 16), 256, 0, stream>>>(qws, kws, vtws, ows);
  cvt1_kernel  <<<dim3(1024), 256, 0, stream>>>(Wo, wo_b, (DM * DM) / 4);
  oproj256_kernel<<<dim3(128), 512, 0, stream>>>(ows, wo_b, bo, out);
}

// Round 4
// 263.142 us; speedup vs baseline: 1.0660x; 1.0224x over previous
//
#include <hip/hip_runtime.h>
#include <hip/hip_bf16.h>

typedef __attribute__((ext_vector_type(8))) short short8;
typedef __attribute__((ext_vector_type(4))) short short4v;
typedef __attribute__((ext_vector_type(4))) float floatx4;
typedef __attribute__((ext_vector_type(2))) unsigned int uint2v;
typedef unsigned short u16;

#define B_SZ 4
#define NH   16
#define SEQ  2048
#define DM   1024
#define DK   64
#define M_ROWS (B_SZ * SEQ)   // 8192

__device__ __forceinline__ u16 f2bf(float f) {
  unsigned u = __float_as_uint(f);
  u += 0x7fff + ((u >> 16) & 1);   // RNE
  return (u16)(u >> 16);
}

// packed f32x2 -> bf16x2 (RNE), single instruction
__device__ __forceinline__ unsigned cvt_pk_bf16(float lo, float hi) {
  unsigned r;
  asm("v_cvt_pk_bf16_f32 %0, %1, %2" : "=v"(r) : "v"(lo), "v"(hi));
  return r;
}

// async global->LDS: dest = wave-uniform base + lane*16B (verified constraint)
__device__ __forceinline__ void async_copy16(const u16* g, const short* lds) {
  __builtin_amdgcn_global_load_lds(
      (const __attribute__((address_space(1))) void*)g,
      (__attribute__((address_space(3))) void*)lds,
      16, 0, 0);
}

#define BAR() do { __builtin_amdgcn_s_barrier(); asm volatile("" ::: "memory"); } while (0)
#define WAIT_LGKM0() asm volatile("s_waitcnt lgkmcnt(0)" ::: "memory")

// ---------------------------------------------------------------------------
// cvt4: fp32->bf16 for x (y=0) and Wq/Wk/Wv (y=1..3). grid=(1024,4).
// ---------------------------------------------------------------------------
__global__ __launch_bounds__(256)
void cvt4_kernel(const float* __restrict__ x,
                 const float* __restrict__ wq, const float* __restrict__ wk,
                 const float* __restrict__ wv,
                 u16* __restrict__ xb, u16* __restrict__ wb)
{
  const int y = blockIdx.y;
  const float* src; u16* dst; int n4;
  if (y == 0)      { src = x;  dst = xb;                 n4 = (M_ROWS * DM) / 4; }
  else if (y == 1) { src = wq; dst = wb;                 n4 = (DM * DM) / 4; }
  else if (y == 2) { src = wk; dst = wb + DM * DM;       n4 = (DM * DM) / 4; }
  else             { src = wv; dst = wb + 2 * DM * DM;   n4 = (DM * DM) / 4; }
  for (int i = blockIdx.x * 256 + threadIdx.x; i < n4; i += gridDim.x * 256) {
    floatx4 v = ((const floatx4*)src)[i];
    short4v s;
#pragma unroll
    for (int e = 0; e < 4; ++e) s[e] = (short)f2bf(v[e]);
    ((short4v*)dst)[i] = s;
  }
}

__global__ __launch_bounds__(256)
void cvt1_kernel(const float* __restrict__ in, u16* __restrict__ out, int n4)
{
  for (int i = blockIdx.x * 256 + threadIdx.x; i < n4; i += gridDim.x * 256) {
    floatx4 v = ((const floatx4*)in)[i];
    short4v s;
#pragma unroll
    for (int e = 0; e < 4; ++e) s[e] = (short)f2bf(v[e]);
    ((short4v*)out)[i] = s;
  }
}

// ---------------------------------------------------------------------------
// 256x256 / BK=64 / 8-wave / 8-phase GEMM core (T2+T3+T4+T5 template).
// (unchanged from round 1 -- passed, region ledger verified)
// ---------------------------------------------------------------------------
__device__ __forceinline__ void stage_tile_half(
    const u16* __restrict__ src,   // element (row0_of_half, k0)
    short* dst,                    // LDS base of this 128x64 half
    int wid, int lane)
{
#pragma unroll
  for (int j = 0; j < 2; ++j) {
    const int oct = wid + j * 8;                 // 0..15 (8 rows each)
    const int row = oct * 8 + (lane >> 3);
    const int cu  = (lane & 7) ^ (lane >> 3);    // pre-swizzled col-unit (16B)
    async_copy16(src + (size_t)row * DM + cu * 8, dst + oct * 512);
  }
}

__device__ __forceinline__ void gemm256_core(
    const u16* __restrict__ A, const u16* __restrict__ B,
    int m0, int n0, floatx4 acc[8][4])
{
  __shared__ short smem[65536];                  // 128 KiB: 2 x (A 16K + B 16K)

  const int tid  = threadIdx.x;
  const int wid  = tid >> 6;
  const int lane = tid & 63;
  const int wm   = wid >> 2, wn = wid & 3;       // wave grid 2(M) x 4(N)
  const int quad = lane >> 4, l16 = lane & 15;
  const int swz  = l16 & 7;                      // row&7 == l16&7 for all frags

  short* sA_[2] = { smem,         smem + 32768 };
  short* sB_[2] = { smem + 16384, smem + 49152 };

#pragma unroll
  for (int mi = 0; mi < 8; ++mi)
#pragma unroll
    for (int ni = 0; ni < 4; ++ni)
      acc[mi][ni] = floatx4{0.f, 0.f, 0.f, 0.f};

  const u16* Abase = A + (size_t)m0 * DM;
  const u16* Bbase = B + (size_t)n0 * DM;

  // ---- prologue: stage tiles 0 (buf0) and 1 (buf1), 8 loads each ----
#pragma unroll
  for (int t = 0; t < 2; ++t) {
    const int kof = t * 64;
    stage_tile_half(Abase + kof,                    sA_[t],        wid, lane);
    stage_tile_half(Abase + (size_t)128 * DM + kof, sA_[t] + 8192, wid, lane);
    stage_tile_half(Bbase + kof,                    sB_[t],        wid, lane);
    stage_tile_half(Bbase + (size_t)128 * DM + kof, sB_[t] + 8192, wid, lane);
  }
  asm volatile("s_waitcnt vmcnt(8)" ::: "memory");   // tile0 landed
  BAR();

  short8 af[4][2], bf0[2][2], bf1[2][2];

  for (int i = 0; i < 8; ++i) {                  // tiles 2i, 2i+1
    const bool nl = (i < 7);                     // stage tiles 2i+2 / 2i+3
#pragma unroll
    for (int half = 0; half < 2; ++half) {
      short* cA = sA_[half];
      short* cB = sB_[half];
      const int kof_n = (2 * i + 2 + half) * 64; // staging k-offset (if nl)

      // ---- phase 1: ds_read A-lo (8) + B-lo (4); MFMA m-lo x n-lo ----
#pragma unroll
      for (int mi = 0; mi < 4; ++mi)
#pragma unroll
        for (int kk = 0; kk < 2; ++kk)
          af[mi][kk] = *(const short8*)(cA + (wm * 128 + mi * 16 + l16) * 64
                                           + (((kk * 4 + quad) ^ swz) << 3));
#pragma unroll
      for (int ni = 0; ni < 2; ++ni)
#pragma unroll
        for (int kk = 0; kk < 2; ++kk)
          bf0[ni][kk] = *(const short8*)(cB + (wn * 64 + ni * 16 + l16) * 64
                                            + (((kk * 4 + quad) ^ swz) << 3));
      BAR();
      WAIT_LGKM0();
      __builtin_amdgcn_s_setprio(1);
#pragma unroll
      for (int mi = 0; mi < 4; ++mi)
#pragma unroll
        for (int ni = 0; ni < 2; ++ni)
#pragma unroll
          for (int kk = 0; kk < 2; ++kk)
            acc[mi][ni] = __builtin_amdgcn_mfma_f32_16x16x32_bf16(
                af[mi][kk], bf0[ni][kk], acc[mi][ni], 0, 0, 0);
      __builtin_amdgcn_s_setprio(0);
      BAR();

      // ---- phase 2: ds_read B-hi (4); MFMA m-lo x n-hi ----
#pragma unroll
      for (int ni = 0; ni < 2; ++ni)
#pragma unroll
        for (int kk = 0; kk < 2; ++kk)
          bf1[ni][kk] = *(const short8*)(cB + (wn * 64 + (2 + ni) * 16 + l16) * 64
                                            + (((kk * 4 + quad) ^ swz) << 3));
      BAR();
      WAIT_LGKM0();
      __builtin_amdgcn_s_setprio(1);
#pragma unroll
      for (int mi = 0; mi < 4; ++mi)
#pragma unroll
        for (int ni = 0; ni < 2; ++ni)
#pragma unroll
          for (int kk = 0; kk < 2; ++kk)
            acc[mi][2 + ni] = __builtin_amdgcn_mfma_f32_16x16x32_bf16(
                af[mi][kk], bf1[ni][kk], acc[mi][2 + ni], 0, 0, 0);
      __builtin_amdgcn_s_setprio(0);
      BAR();

      // ---- phase 3: ds_read A-hi (8, reuse af); stage B(next) both halves;
      //      MFMA m-hi x n-hi ----  (B reads all drained by ph2 close)
#pragma unroll
      for (int mi = 0; mi < 4; ++mi)
#pragma unroll
        for (int kk = 0; kk < 2; ++kk)
          af[mi][kk] = *(const short8*)(cA + (wm * 128 + (4 + mi) * 16 + l16) * 64
                                           + (((kk * 4 + quad) ^ swz) << 3));
      if (nl) {
        stage_tile_half(Bbase + kof_n,                    cB,        wid, lane);
        stage_tile_half(Bbase + (size_t)128 * DM + kof_n, cB + 8192, wid, lane);
      }
      BAR();
      WAIT_LGKM0();
      __builtin_amdgcn_s_setprio(1);
#pragma unroll
      for (int mi = 0; mi < 4; ++mi)
#pragma unroll
        for (int ni = 0; ni < 2; ++ni)
#pragma unroll
          for (int kk = 0; kk < 2; ++kk)
            acc[4 + mi][2 + ni] = __builtin_amdgcn_mfma_f32_16x16x32_bf16(
                af[mi][kk], bf1[ni][kk], acc[4 + mi][2 + ni], 0, 0, 0);
      __builtin_amdgcn_s_setprio(0);
      BAR();

      // ---- phase 4: stage A(next) both halves; counted vmcnt;
      //      MFMA m-hi x n-lo ----  (A reads all drained by ph3 close)
      if (nl) {
        stage_tile_half(Abase + kof_n,                    cA,        wid, lane);
        stage_tile_half(Abase + (size_t)128 * DM + kof_n, cA + 8192, wid, lane);
        asm volatile("s_waitcnt vmcnt(8)" ::: "memory");  // tile t+1 landed
      } else {
        asm volatile("s_waitcnt vmcnt(0)" ::: "memory");  // drain final tiles
      }
      BAR();
      __builtin_amdgcn_s_setprio(1);
#pragma unroll
      for (int mi = 0; mi < 4; ++mi)
#pragma unroll
        for (int ni = 0; ni < 2; ++ni)
#pragma unroll
          for (int kk = 0; kk < 2; ++kk)
            acc[4 + mi][ni] = __builtin_amdgcn_mfma_f32_16x16x32_bf16(
                af[mi][kk], bf0[ni][kk], acc[4 + mi][ni], 0, 0, 0);
      __builtin_amdgcn_s_setprio(0);
      BAR();
    }
  }
}

// ---------------------------------------------------------------------------
// Fused QKV projection, 256^2 tiles. grid = (384): [0,128) Q, [128,256) K,
// [256,384) V^T (operands swapped: C[e][s] = sum_d Wv[e][d] x[s][d], so the
// (b,h,d,s) store is contiguous in s -- no 4KB-stride scatter).
// ---------------------------------------------------------------------------
__global__ __launch_bounds__(512, 2)
void qkv256_kernel(const u16* __restrict__ xb, const u16* __restrict__ wb,
                   const float* __restrict__ bq, const float* __restrict__ bk,
                   const float* __restrict__ bv,
                   u16* __restrict__ Qo, u16* __restrict__ Ko, u16* __restrict__ Vto)
{
  const int bx = blockIdx.x;
  const int wg = (bx & 7) * 48 + (bx >> 3);      // bijective XCD swizzle (384%8==0)
  const int mat = wg >> 7;
  const int r   = wg & 127;

  int m0, n0;
  const u16 *A, *Bm;
  if (mat < 2) { m0 = (r >> 2) * 256; n0 = (r & 3) * 256; A = xb; Bm = wb + (size_t)mat * DM * DM; }
  else         { m0 = (r & 3) * 256;  n0 = (r >> 2) * 256; A = wb + (size_t)2 * DM * DM; Bm = xb; }

  floatx4 acc[8][4];
  gemm256_core(A, Bm, m0, n0, acc);

  const int tid = threadIdx.x;
  const int wid = tid >> 6, lane = tid & 63;
  const int wm = wid >> 2, wn = wid & 3;
  const int quad = lane >> 4, l16 = lane & 15;

  if (mat < 2) {
    u16* dst = (mat == 0) ? Qo : Ko;
    const float* bias = (mat == 0) ? bq : bk;
#pragma unroll
    for (int ni = 0; ni < 4; ++ni) {
      const int n = n0 + wn * 64 + ni * 16 + l16;
      const float bb = bias[n];
      const int h = n >> 6, d = n & 63;
#pragma unroll
      for (int mi = 0; mi < 8; ++mi)
#pragma unroll
        for (int rr = 0; rr < 4; ++rr) {
          const int m = m0 + wm * 128 + mi * 16 + quad * 4 + rr;
          const int b = m >> 11, s = m & 2047;
          dst[((size_t)(b * NH + h) * SEQ + s) * DK + d] = f2bf(acc[mi][ni][rr] + bb);
        }
    }
  } else {
#pragma unroll
    for (int mi = 0; mi < 8; ++mi)
#pragma unroll
      for (int rr = 0; rr < 4; ++rr) {
        const int m = m0 + wm * 128 + mi * 16 + quad * 4 + rr;   // e in [0,1024)
        const float bb = bv[m];
        const int h = m >> 6, d = m & 63;
#pragma unroll
        for (int ni = 0; ni < 4; ++ni) {
          const int n = n0 + wn * 64 + ni * 16 + l16;            // (b,s) in [0,8192)
          const int b = n >> 11, s = n & 2047;
          Vto[((size_t)(b * NH + h) * DK + d) * SEQ + s] = f2bf(acc[mi][ni][rr] + bb);
        }
      }
  }
}

// ---------------------------------------------------------------------------
// Flash attention, causal, exp2-domain, no-rescale online softmax.
// grid = (64 bh, 16 qt-reversed). Block = 128 q-rows, 4 waves x 32 rows.
//
// Round-2 rework: SWAPPED QK^T -- sc = mfma(K, Q) gives D[key][query]:
// lane l16 = q-row, (quad*4+r) = key.  P is lane-local per q-row, so:
//   * P->bf16 via v_cvt_pk_bf16_f32 pairs (8 packs vs 32 manual RNE)
//   * P staged with 4 ds_write_b64 (vs 16 scalar ds_write_u16)
//   * Ps is 16 rows/wave (reused across qp): LDS 34.8KB -> 25.6KB
// K/Q fragments are identical either way (A.m and B.n are both lane&15),
// so kf/qf loads, PV, l-sum (vone MFMA) and epilogue are unchanged.
// ---------------------------------------------------------------------------
#define AT_STR 72
__global__ __launch_bounds__(256, 2)
void attn_kernel(const u16* __restrict__ Q, const u16* __restrict__ Kx,
                 const u16* __restrict__ Vt, u16* __restrict__ O)
{
  __shared__ short Ks[64 * 64];
  __shared__ short Vs[64 * 64];
  __shared__ __align__(16) short Ps[4 * 16 * AT_STR];   // 16 rows per wave

  const int bh  = blockIdx.x;
  const int qtb = 15 - (int)blockIdx.y;
  const int q0  = qtb * 128;
  const int tid = threadIdx.x;
  const int w = tid >> 6, lane = tid & 63;
  const int quad = lane >> 4, l16 = lane & 15;
  const int r8 = lane >> 3, c8 = lane & 7;

  const u16* Qh = Q  + (size_t)bh * SEQ * DK;
  const u16* Kh = Kx + (size_t)bh * SEQ * DK;
  const u16* Vh = Vt + (size_t)bh * DK * SEQ;

  short8 qf[2][2];
#pragma unroll
  for (int qp = 0; qp < 2; ++qp) {
    const int qrow = q0 + w * 32 + qp * 16 + l16;
#pragma unroll
    for (int h = 0; h < 2; ++h)
      qf[qp][h] = *(const short8*)(Qh + (size_t)qrow * DK + h * 32 + quad * 8);
  }

  short8 vone;
#pragma unroll
  for (int j = 0; j < 8; ++j) vone[j] = (l16 == 0) ? (short)0x3F80 : (short)0;

  floatx4 o[2][4], ls[2];
#pragma unroll
  for (int qp = 0; qp < 2; ++qp) {
    ls[qp] = floatx4{0.f, 0.f, 0.f, 0.f};
#pragma unroll
    for (int dt = 0; dt < 4; ++dt) o[qp][dt] = floatx4{0.f, 0.f, 0.f, 0.f};
  }

  const float SC2 = 0.18033688011f;   // (1/8) * log2(e)
  const int ktmax = 2 * qtb + 2;
  short* Pw = Ps + w * 16 * AT_STR;   // this wave's 16-row P buffer

  for (int kt = 0; kt < ktmax; ++kt) {
    const int k0 = kt * 64;
    __syncthreads();
#pragma unroll
    for (int c = 0; c < 2; ++c) {
      const int row8 = w * 16 + c * 8;   // wave-uniform
      const int sw   = (c8 ^ r8) * 8;
      async_copy16(Kh + (size_t)(k0 + row8 + r8) * DK + sw, Ks + row8 * 64);
      async_copy16(Vh + (size_t)(row8 + r8) * SEQ + k0 + sw, Vs + row8 * 64);
    }
    __syncthreads();

    short8 kf[4][2], vf[4][2];
#pragma unroll
    for (int nt = 0; nt < 4; ++nt)
#pragma unroll
      for (int h = 0; h < 2; ++h) {
        kf[nt][h] = *(const short8*)(Ks + (nt * 16 + l16) * 64 + (((h * 4 + quad) ^ (l16 & 7)) * 8));
        vf[nt][h] = *(const short8*)(Vs + (nt * 16 + l16) * 64 + (((h * 4 + quad) ^ (l16 & 7)) * 8));
      }

#pragma unroll
    for (int qp = 0; qp < 2; ++qp) {
      const int frag0 = q0 + w * 32 + qp * 16;
      if (k0 <= frag0 + 15) {
        // swapped QK^T: D[key][query] -> lane holds q-row = l16,
        // keys k0 + nt*16 + quad*4 + r  (r = reg)
        floatx4 sc[4];
#pragma unroll
        for (int nt = 0; nt < 4; ++nt) {
          floatx4 z = floatx4{0.f, 0.f, 0.f, 0.f};
          z = __builtin_amdgcn_mfma_f32_16x16x32_bf16(kf[nt][0], qf[qp][0], z, 0, 0, 0);
          z = __builtin_amdgcn_mfma_f32_16x16x32_bf16(kf[nt][1], qf[qp][1], z, 0, 0, 0);
          sc[nt] = z;
        }
        const bool diag = (k0 + 63 > frag0);
        const int qrow = frag0 + l16;
#pragma unroll
        for (int nt = 0; nt < 4; ++nt)
#pragma unroll
          for (int r = 0; r < 4; ++r) {
            float s = sc[nt][r] * SC2;
            if (diag) {
              const int col = k0 + nt * 16 + quad * 4 + r;
              if (col > qrow) s = -1e30f;
            }
            sc[nt][r] = __builtin_amdgcn_exp2f(s);
          }
        // pack pairs + b64 stores: row = l16 (own q-row), cols nt*16+quad*4..+3
#pragma unroll
        for (int nt = 0; nt < 4; ++nt) {
          uint2v wv2;
          wv2[0] = cvt_pk_bf16(sc[nt][0], sc[nt][1]);
          wv2[1] = cvt_pk_bf16(sc[nt][2], sc[nt][3]);
          *(short4v*)(Pw + l16 * AT_STR + nt * 16 + quad * 4) =
              __builtin_bit_cast(short4v, wv2);
        }
        asm volatile("" ::: "memory");   // keep pf reads after P writes
        short8 pf[2];
#pragma unroll
        for (int h = 0; h < 2; ++h)
          pf[h] = *(const short8*)(Pw + l16 * AT_STR + h * 32 + quad * 8);
#pragma unroll
        for (int dt = 0; dt < 4; ++dt) {
          o[qp][dt] = __builtin_amdgcn_mfma_f32_16x16x32_bf16(pf[0], vf[dt][0], o[qp][dt], 0, 0, 0);
          o[qp][dt] = __builtin_amdgcn_mfma_f32_16x16x32_bf16(pf[1], vf[dt][1], o[qp][dt], 0, 0, 0);
        }
        ls[qp] = __builtin_amdgcn_mfma_f32_16x16x32_bf16(pf[0], vone, ls[qp], 0, 0, 0);
        ls[qp] = __builtin_amdgcn_mfma_f32_16x16x32_bf16(pf[1], vone, ls[qp], 0, 0, 0);
      }
    }
  }

  const int b = bh >> 4, h = bh & 15;
#pragma unroll
  for (int qp = 0; qp < 2; ++qp) {
    const int frag0 = q0 + w * 32 + qp * 16;
#pragma unroll
    for (int r = 0; r < 4; ++r) {
      const float lv  = __shfl(ls[qp][r], lane & 48);
      const float inv = 1.0f / fmaxf(lv, 1e-20f);
      const int row   = frag0 + quad * 4 + r;
      const size_t base = ((size_t)b * SEQ + row) * DM + h * DK;
#pragma unroll
      for (int dt = 0; dt < 4; ++dt)
        O[base + dt * 16 + l16] = f2bf(o[qp][dt][r] * inv);
    }
  }
}

// ---------------------------------------------------------------------------
// Output projection: out = O'(bf16) @ Wo_b^T + bo, fp32 out. grid = (128).
// ---------------------------------------------------------------------------
__global__ __launch_bounds__(512, 2)
void oproj256_kernel(const u16* __restrict__ A, const u16* __restrict__ Wob,
                     const float* __restrict__ bo, float* __restrict__ out)
{
  const int bx = blockIdx.x;
  const int wg = (bx & 7) * 16 + (bx >> 3);      // 128 % 8 == 0
  const int m0 = (wg >> 2) * 256, n0 = (wg & 3) * 256;

  floatx4 acc[8][4];
  gemm256_core(A, Wob, m0, n0, acc);

  const int tid = threadIdx.x;
  const int wid = tid >> 6, lane = tid & 63;
  const int wm = wid >> 2, wn = wid & 3;
  const int quad = lane >> 4, l16 = lane & 15;

#pragma unroll
  for (int ni = 0; ni < 4; ++ni) {
    const int n = n0 + wn * 64 + ni * 16 + l16;
    const float bb = bo[n];
#pragma unroll
    for (int mi = 0; mi < 8; ++mi)
#pragma unroll
      for (int rr = 0; rr < 4; ++rr) {
        const int m = m0 + wm * 128 + mi * 16 + quad * 4 + rr;
        out[(size_t)m * DM + n] = acc[mi][ni][rr] + bb;
      }
  }
}

extern "C" void kernel_launch(void* const* d_in, const int* in_sizes, int n_in,
                              void* d_out, int out_size, void* d_ws, size_t ws_size,
                              hipStream_t stream)
{
  const float* x  = (const float*)d_in[0];
  const float* Wq = (const float*)d_in[1];
  const float* bq = (const float*)d_in[2];
  const float* Wk = (const float*)d_in[3];
  const float* bk = (const float*)d_in[4];
  const float* Wv = (const float*)d_in[5];
  const float* bv = (const float*)d_in[6];
  const float* Wo = (const float*)d_in[7];
  const float* bo = (const float*)d_in[8];
  float* out = (float*)d_out;

  // ws (64 MiB): Q, K, Vt, O'  (qws doubles as Wo_b after attn)
  u16* qws  = (u16*)d_ws;                       // (b,h,s,d)  bf16, 16 MiB
  u16* kws  = qws  + (size_t)M_ROWS * DM;       // (b,h,s,d)  bf16, 16 MiB
  u16* vtws = kws  + (size_t)M_ROWS * DM;       // (b,h,d,s)  bf16, 16 MiB
  u16* ows  = vtws + (size_t)M_ROWS * DM;       // O' (b,s,h*d) bf16, 16 MiB

  // d_out doubles as scratch until oproj overwrites all of it:
  //   [0, 16 MiB)  : x bf16
  //   [16, 22 MiB) : Wq/Wk/Wv bf16 packed [3][DM][DM]
  u16* xb = (u16*)d_out;
  u16* wb = xb + (size_t)M_ROWS * DM;
  u16* wo_b = qws;                              // qws dead after attn

  cvt4_kernel  <<<dim3(1024, 4), 256, 0, stream>>>(x, Wq, Wk, Wv, xb, wb);
  qkv256_kernel<<<dim3(384), 512, 0, stream>>>(xb, wb, bq, bk, bv, qws, kws, vtws);
  attn_kernel  <<<dim3(64, 16), 256, 0, stream>>>(qws, kws, vtws, ows);
  cvt1_kernel  <<<dim3(1024), 256, 0, stream>>>(Wo, wo_b, (DM * DM) / 4);
  oproj256_kernel<<<dim3(128), 512, 0, stream>>>(ows, wo_b, bo, out);
}